// Round 8
// baseline (92.642 us; speedup 1.0000x reference)
//
#include <hip/hip_runtime.h>

#define BB 2
#define NN 512
#define FF 128
#define HH 256
#define TI 4     // i-rows per K2 block
#define K1BN 32  // bn per K1 block (8 per wave)

typedef float v2f __attribute__((ext_vector_type(2)));
typedef _Float16 v2h __attribute__((ext_vector_type(2)));
typedef unsigned int u32;
__device__ __forceinline__ v2f splat2(float s) { return (v2f){s, s}; }

#if defined(__has_builtin)
#if __has_builtin(__builtin_amdgcn_fdot2)
#define HAVE_DOT2 1
#endif
#endif

__device__ __forceinline__ u32 pack16(float a, float b) {
  v2h p; p.x = (_Float16)a; p.y = (_Float16)b;
  return __builtin_bit_cast(u32, p);
}
__device__ __forceinline__ v2h as_v2h(u32 u) { return __builtin_bit_cast(v2h, u); }

// ---------------- K1: s16 / qT16 = f16-packed x . w1 halves ----------------
// Grid (32, 8), 256 thr. Block: 32 bn x 64 h'. Wave: 8 bn (8 acc chains ->
// 32 FMA per ds_read_b128; LDS-pipe load halved vs 4-bn version).
__global__ __launch_bounds__(256) void k1_pq(const float* __restrict__ x,
    const float* __restrict__ w1, const float* __restrict__ b1,
    const float* __restrict__ w2,
    u32* __restrict__ s16, u32* __restrict__ q16, u32* __restrict__ w216) {
  __shared__ __align__(16) float w1_l[64][FF];   // 32 KB, rotated
  __shared__ float tmp[64][33];                  // 8.25 KB transpose (q-half)
  const int t   = threadIdx.x;
  const int bn0 = blockIdx.x * K1BN;
  const int h0  = blockIdx.y * 64;               // h' base
  const bool qh = (h0 >= HH);
  const int rowbase = qh ? (h0 - HH) : h0;
  const int colbase = qh ? FF : 0;

  // stage w1 tile: element (r, f) stored at column (f + 4r) & 127
  #pragma unroll
  for (int k = 0; k < 8; ++k) {
    int idx = t + 256 * k;
    int r = idx >> 5, c4 = (idx & 31) * 4;
    float4 v = *(const float4*)(w1 + (rowbase + r) * (2 * FF) + colbase + c4);
    *(float4*)&w1_l[r][(c4 + 4 * r) & 127] = v;
  }
  __syncthreads();

  const int l  = t & 63;
  const int sb = __builtin_amdgcn_readfirstlane(t >> 6);   // wave-uniform bn group
  const float* xr = x + (bn0 + sb * 8) * FF;
  float acc[8];
  #pragma unroll
  for (int r = 0; r < 8; ++r) acc[r] = 0.f;

  #pragma unroll 4
  for (int f4 = 0; f4 < FF; f4 += 4) {
    float4 wv = *(float4*)&w1_l[l][(f4 + 4 * l) & 127];
    #pragma unroll
    for (int r = 0; r < 8; ++r) {
      float4 xv = *(const float4*)(xr + r * FF + f4);      // uniform -> s_load
      acc[r] = fmaf(xv.x, wv.x, acc[r]);
      acc[r] = fmaf(xv.y, wv.y, acc[r]);
      acc[r] = fmaf(xv.z, wv.z, acc[r]);
      acc[r] = fmaf(xv.w, wv.w, acc[r]);
    }
  }

  const int bn = bn0 + sb * 8;
  if (!qh) {
    float bv = b1[h0 + l];
    ushort* sp = (ushort*)s16;                   // s16 as [bn][h] f16
    #pragma unroll
    for (int r = 0; r < 8; ++r)
      sp[(bn + r) * HH + h0 + l] = __builtin_bit_cast(ushort, (_Float16)(acc[r] + bv));
  } else {
    #pragma unroll
    for (int r = 0; r < 8; ++r) tmp[l][sb * 8 + r] = acc[r];
    __syncthreads();
    #pragma unroll
    for (int k = 0; k < 4; ++k) {                // 32 hp x 32 bn packed pairs
      int idx = t + 256 * k;
      int rp = idx >> 5, c = idx & 31;
      q16[((h0 - HH) / 2 + rp) * (BB * NN) + bn0 + c] =
          pack16(tmp[2 * rp][c], tmp[2 * rp + 1][c]);
    }
    if (blockIdx.x == 0 && h0 == HH && t < HH / 2)
      w216[t] = pack16(w2[2 * t], w2[2 * t + 1]);
  }
}

// ---------------- K2: e -> leaky -> mask -> softmax -> next_h ----------------
// (unchanged from round 7 — proven, at its e-phase VALU floor)
__global__ __launch_bounds__(1024) void k2_attn(const u32* __restrict__ s16,
    const u32* __restrict__ q16, const u32* __restrict__ w216,
    const float* __restrict__ x, const float* __restrict__ b2,
    const int* __restrict__ adj, float* __restrict__ out) {
  __shared__ __align__(16) float pe[2][TI][NN];        // 16 KB (h-half partials)
  __shared__ __align__(16) float e_l[TI][NN];          // 8 KB
  __shared__ __align__(16) float part_l[16][TI][FF];   // 32 KB
  __shared__ float red_m[TI][4];
  __shared__ float red_s[TI][4];

  const int blk = blockIdx.x;
  const int b   = blk >> 7;                 // / 128
  const int i0  = (blk & 127) * TI;
  const int t   = threadIdx.x;              // 0..1023
  const int wv  = __builtin_amdgcn_readfirstlane(t >> 6);
  const int ln  = t & 63;

  // ---- e-phase ----
  {
    const int hg = wv >> 3;                 // h-pair range [hg*64, +64)
    const int sl = wv & 7;                  // j slice, lane j = sl*64+ln
    const int j  = sl * 64 + ln;
    const u32* qp = q16 + hg * 64 * (BB * NN) + b * NN + j;
    const u32* sp = s16 + (b * NN + i0) * (HH / 2) + hg * 64;  // uniform -> s_load
    const u32* wp = w216 + hg * 64;                            // uniform -> s_load
    float a0 = 0.f, a1 = 0.f, a2 = 0.f, a3 = 0.f;
#ifdef HAVE_DOT2
    const v2h z2 = {(_Float16)0.f, (_Float16)0.f};
    #pragma unroll 8
    for (int hp = 0; hp < 64; ++hp) {
      v2h q2 = as_v2h(qp[hp * (BB * NN)]);  // coalesced 4B/lane
      v2h wh = as_v2h(wp[hp]);
      v2h s0 = as_v2h(sp[hp]);
      v2h s1 = as_v2h(sp[HH / 2 + hp]);
      v2h s2 = as_v2h(sp[2 * (HH / 2) + hp]);
      v2h s3 = as_v2h(sp[3 * (HH / 2) + hp]);
      a0 = __builtin_amdgcn_fdot2(__builtin_elementwise_max(s0 + q2, z2), wh, a0, false);
      a1 = __builtin_amdgcn_fdot2(__builtin_elementwise_max(s1 + q2, z2), wh, a1, false);
      a2 = __builtin_amdgcn_fdot2(__builtin_elementwise_max(s2 + q2, z2), wh, a2, false);
      a3 = __builtin_amdgcn_fdot2(__builtin_elementwise_max(s3 + q2, z2), wh, a3, false);
    }
#else
    #pragma unroll 8
    for (int hp = 0; hp < 64; ++hp) {
      v2h q2 = as_v2h(qp[hp * (BB * NN)]);
      v2h wh = as_v2h(wp[hp]);
      v2h s0 = as_v2h(sp[hp]);
      v2h s1 = as_v2h(sp[HH / 2 + hp]);
      v2h s2 = as_v2h(sp[2 * (HH / 2) + hp]);
      v2h s3 = as_v2h(sp[3 * (HH / 2) + hp]);
      float qx = (float)q2.x, qy = (float)q2.y;
      float wx = (float)wh.x, wy = (float)wh.y;
      a0 = fmaf(fmaxf((float)s0.x + qx, 0.f), wx, a0);
      a0 = fmaf(fmaxf((float)s0.y + qy, 0.f), wy, a0);
      a1 = fmaf(fmaxf((float)s1.x + qx, 0.f), wx, a1);
      a1 = fmaf(fmaxf((float)s1.y + qy, 0.f), wy, a1);
      a2 = fmaf(fmaxf((float)s2.x + qx, 0.f), wx, a2);
      a2 = fmaf(fmaxf((float)s2.y + qy, 0.f), wy, a2);
      a3 = fmaf(fmaxf((float)s3.x + qx, 0.f), wx, a3);
      a3 = fmaf(fmaxf((float)s3.y + qy, 0.f), wy, a3);
    }
#endif
    pe[hg][0][j] = a0; pe[hg][1][j] = a1;
    pe[hg][2][j] = a2; pe[hg][3][j] = a3;
  }
  __syncthreads();

  // ---- combine h-halves + bias + leaky + mask ----
  {
    const float b2v = b2[0];
    #pragma unroll
    for (int r = 0; r < 2; ++r) {
      int idx = t + 1024 * r;               // 2048 cells of [ti][j]
      int ti = idx >> 9, j2 = idx & 511;
      float e = pe[0][ti][j2] + pe[1][ti][j2] + b2v;
      e = e > 0.f ? e : 0.04f * e;
      int av = adj[(b * NN + i0 + ti) * NN + j2];
      e_l[ti][j2] = (av > 0) ? e : -9.0e15f;
    }
  }
  __syncthreads();

  // ---- softmax: wave = (ti = wv>>2, j-quarter = wv&3), 2 vals/lane ----
  {
    const int ti = wv >> 2, qtr = wv & 3;
    float2 v = *(float2*)&e_l[ti][qtr * 128 + 2 * ln];
    float m = fmaxf(v.x, v.y);
    #pragma unroll
    for (int off = 32; off > 0; off >>= 1) m = fmaxf(m, __shfl_xor(m, off, 64));
    if (ln == 0) red_m[ti][qtr] = m;
    __syncthreads();
    m = fmaxf(fmaxf(red_m[ti][0], red_m[ti][1]), fmaxf(red_m[ti][2], red_m[ti][3]));
    v.x = __expf(v.x - m); v.y = __expf(v.y - m);
    float zs = v.x + v.y;
    #pragma unroll
    for (int off = 32; off > 0; off >>= 1) zs += __shfl_xor(zs, off, 64);
    if (ln == 0) red_s[ti][qtr] = zs;
    __syncthreads();
    float inv = 1.f / ((red_s[ti][0] + red_s[ti][1]) + (red_s[ti][2] + red_s[ti][3]));
    v.x *= inv; v.y *= inv;
    *(float2*)&e_l[ti][qtr * 128 + 2 * ln] = v;
  }
  __syncthreads();

  // attention[0,0,:] extra output
  if (blk == 0 && t < NN) out[BB * NN * FF + t] = e_l[0][t];

  // ---- next_h: wave wv owns 32 j-rows (x read once per block); lane = f-pair ----
  {
    const int jb = wv * 32;
    const int f2 = 2 * ln;
    v2f acc[TI];
    #pragma unroll
    for (int ti = 0; ti < TI; ++ti) acc[ti] = (v2f){0.f, 0.f};

    #pragma unroll 2
    for (int g = 0; g < 8; ++g) {
      const int j0 = jb + g * 4;
      float4 aa[TI];
      #pragma unroll
      for (int ti = 0; ti < TI; ++ti) aa[ti] = *(float4*)&e_l[ti][j0];  // broadcast b128
      #pragma unroll
      for (int k = 0; k < 4; ++k) {
        v2f x2 = *(const v2f*)(x + (b * NN + j0 + k) * FF + f2);        // coalesced 512B
        #pragma unroll
        for (int ti = 0; ti < TI; ++ti) {
          float w = (k == 0) ? aa[ti].x : (k == 1) ? aa[ti].y : (k == 2) ? aa[ti].z : aa[ti].w;
          acc[ti] = __builtin_elementwise_fma(splat2(w), x2, acc[ti]);
        }
      }
    }
    #pragma unroll
    for (int ti = 0; ti < TI; ++ti) *(v2f*)&part_l[wv][ti][f2] = acc[ti];
  }
  __syncthreads();
  if (t < TI * FF) {                         // 512 cells
    const int ti = t >> 7, f = t & 127;
    float r = 0.f;
    #pragma unroll
    for (int w = 0; w < 16; ++w) r += part_l[w][ti][f];
    out[(b * NN + i0 + ti) * FF + f] = r;
  }
}

extern "C" void kernel_launch(void* const* d_in, const int* in_sizes, int n_in,
                              void* d_out, int out_size, void* d_ws, size_t ws_size,
                              hipStream_t stream) {
  const float* x   = (const float*)d_in[0];
  const float* w1  = (const float*)d_in[1];
  const float* b1  = (const float*)d_in[2];
  const float* w2  = (const float*)d_in[3];
  const float* b2  = (const float*)d_in[4];
  const int*   adj = (const int*)  d_in[5];
  float* out = (float*)d_out;

  u32* s16  = (u32*)d_ws;                   // [1024][128] u32 (f16 h-pairs) = 512 KB
  u32* q16  = s16 + BB * NN * (HH / 2);     // [128][1024] u32 = 512 KB
  u32* w216 = q16 + (HH / 2) * (BB * NN);   // [128] u32

  dim3 g1(BB * NN / K1BN, (2 * HH) / 64);   // (32, 8) = 256 blocks
  k1_pq  <<<g1, 256, 0, stream>>>(x, w1, b1, w2, s16, q16, w216);
  k2_attn<<<BB * NN / TI, 1024, 0, stream>>>(s16, q16, w216, x, b2, adj, out);
}

// Round 9
// 86.981 us; speedup vs baseline: 1.0651x; 1.0651x over previous
//
#include <hip/hip_runtime.h>

#define BB 2
#define NN 512
#define FF 128
#define HH 256
#define TI 4     // i-rows per K2 block

typedef float v2f __attribute__((ext_vector_type(2)));
typedef _Float16 v2h __attribute__((ext_vector_type(2)));
typedef unsigned int u32;
__device__ __forceinline__ v2f splat2(float s) { return (v2f){s, s}; }

#if defined(__has_builtin)
#if __has_builtin(__builtin_amdgcn_fdot2)
#define HAVE_DOT2 1
#endif
#endif

__device__ __forceinline__ u32 pack16(float a, float b) {
  v2h p; p.x = (_Float16)a; p.y = (_Float16)b;
  return __builtin_bit_cast(u32, p);
}
__device__ __forceinline__ v2h as_v2h(u32 u) { return __builtin_bit_cast(v2h, u); }

// ---------------- K1: s16 / qT16 = f16-packed x . w1 halves ----------------
// Grid (64, 8), 256 thr (2 blocks/CU -> 8 waves/CU: hides mixed s_load/ds_read
// lgkm latency; DO NOT drop to 1 block/CU — round-8 regression, +6.8 us).
// h0 = by*64. by<4 -> s-half (s16[bn][h] f16, +b1 folded);
// by>=4 -> q-half (qT16[hp][bn] u32 = packed h-pair). w216 written by one block.
__global__ __launch_bounds__(256) void k1_pq(const float* __restrict__ x,
    const float* __restrict__ w1, const float* __restrict__ b1,
    const float* __restrict__ w2,
    u32* __restrict__ s16, u32* __restrict__ q16, u32* __restrict__ w216) {
  __shared__ __align__(16) float w1_l[64][FF];   // 32 KB, rotated
  __shared__ float tmp[64][17];                  // transpose buffer (q-half)
  const int t   = threadIdx.x;
  const int bn0 = blockIdx.x * 16;
  const int h0  = blockIdx.y * 64;               // h' base
  const bool qh = (h0 >= HH);
  const int rowbase = qh ? (h0 - HH) : h0;
  const int colbase = qh ? FF : 0;

  #pragma unroll
  for (int k = 0; k < 8; ++k) {
    int idx = t + 256 * k;
    int r = idx >> 5, c4 = (idx & 31) * 4;
    float4 v = *(const float4*)(w1 + (rowbase + r) * (2 * FF) + colbase + c4);
    *(float4*)&w1_l[r][(c4 + 4 * r) & 127] = v;
  }
  __syncthreads();

  const int l  = t & 63;
  const int sb = __builtin_amdgcn_readfirstlane(t >> 6);
  const float* xr = x + (bn0 + sb * 4) * FF;
  float acc0 = 0.f, acc1 = 0.f, acc2 = 0.f, acc3 = 0.f;

  #pragma unroll 4
  for (int f4 = 0; f4 < FF; f4 += 4) {
    float4 wv = *(float4*)&w1_l[l][(f4 + 4 * l) & 127];
    float4 x0 = *(const float4*)(xr + f4);
    float4 x1 = *(const float4*)(xr + FF + f4);
    float4 x2 = *(const float4*)(xr + 2 * FF + f4);
    float4 x3 = *(const float4*)(xr + 3 * FF + f4);
    acc0 = fmaf(x0.x, wv.x, acc0); acc0 = fmaf(x0.y, wv.y, acc0);
    acc0 = fmaf(x0.z, wv.z, acc0); acc0 = fmaf(x0.w, wv.w, acc0);
    acc1 = fmaf(x1.x, wv.x, acc1); acc1 = fmaf(x1.y, wv.y, acc1);
    acc1 = fmaf(x1.z, wv.z, acc1); acc1 = fmaf(x1.w, wv.w, acc1);
    acc2 = fmaf(x2.x, wv.x, acc2); acc2 = fmaf(x2.y, wv.y, acc2);
    acc2 = fmaf(x2.z, wv.z, acc2); acc2 = fmaf(x2.w, wv.w, acc2);
    acc3 = fmaf(x3.x, wv.x, acc3); acc3 = fmaf(x3.y, wv.y, acc3);
    acc3 = fmaf(x3.z, wv.z, acc3); acc3 = fmaf(x3.w, wv.w, acc3);
  }

  const int bn = bn0 + sb * 4;
  if (!qh) {
    float bv = b1[h0 + l];
    ushort* sp = (ushort*)s16;                   // s16 as [bn][h] f16
    sp[(bn    ) * HH + h0 + l] = __builtin_bit_cast(ushort, (_Float16)(acc0 + bv));
    sp[(bn + 1) * HH + h0 + l] = __builtin_bit_cast(ushort, (_Float16)(acc1 + bv));
    sp[(bn + 2) * HH + h0 + l] = __builtin_bit_cast(ushort, (_Float16)(acc2 + bv));
    sp[(bn + 3) * HH + h0 + l] = __builtin_bit_cast(ushort, (_Float16)(acc3 + bv));
  } else {
    tmp[l][sb * 4]     = acc0;
    tmp[l][sb * 4 + 1] = acc1;
    tmp[l][sb * 4 + 2] = acc2;
    tmp[l][sb * 4 + 3] = acc3;
    __syncthreads();
    #pragma unroll
    for (int k = 0; k < 2; ++k) {                // 32 hp x 16 bn packed pairs
      int idx = t + 256 * k;
      int rp = idx >> 4, c = idx & 15;
      q16[((h0 - HH) / 2 + rp) * (BB * NN) + bn0 + c] =
          pack16(tmp[2 * rp][c], tmp[2 * rp + 1][c]);
    }
    if (blockIdx.x == 0 && h0 == HH && t < HH / 2)
      w216[t] = pack16(w2[2 * t], w2[2 * t + 1]);
  }
}

// ---------------- K2: e -> leaky -> mask -> softmax -> next_h ----------------
// Block = (b, 4 i-rows), 1024 threads = 16 waves.
// e-phase: wave = (h-half hg, 64-j slice sl); f16 dot2 (2 MAC/instr), fp32 acc.
__global__ __launch_bounds__(1024) void k2_attn(const u32* __restrict__ s16,
    const u32* __restrict__ q16, const u32* __restrict__ w216,
    const float* __restrict__ x, const float* __restrict__ b2,
    const int* __restrict__ adj, float* __restrict__ out) {
  __shared__ __align__(16) float pe[2][TI][NN];        // 16 KB (h-half partials)
  __shared__ __align__(16) float e_l[TI][NN];          // 8 KB
  __shared__ __align__(16) float part_l[16][TI][FF];   // 32 KB
  __shared__ float red_m[TI][4];
  __shared__ float red_s[TI][4];

  const int blk = blockIdx.x;
  const int b   = blk >> 7;                 // / 128
  const int i0  = (blk & 127) * TI;
  const int t   = threadIdx.x;              // 0..1023
  const int wv  = __builtin_amdgcn_readfirstlane(t >> 6);
  const int ln  = t & 63;

  // ---- e-phase ----
  {
    const int hg = wv >> 3;                 // h-pair range [hg*64, +64)
    const int sl = wv & 7;                  // j slice, lane j = sl*64+ln
    const int j  = sl * 64 + ln;
    const u32* qp = q16 + hg * 64 * (BB * NN) + b * NN + j;
    const u32* sp = s16 + (b * NN + i0) * (HH / 2) + hg * 64;  // uniform -> s_load
    const u32* wp = w216 + hg * 64;                            // uniform -> s_load
    float a0 = 0.f, a1 = 0.f, a2 = 0.f, a3 = 0.f;
#ifdef HAVE_DOT2
    const v2h z2 = {(_Float16)0.f, (_Float16)0.f};
    #pragma unroll 8
    for (int hp = 0; hp < 64; ++hp) {
      v2h q2 = as_v2h(qp[hp * (BB * NN)]);  // coalesced 4B/lane
      v2h wh = as_v2h(wp[hp]);
      v2h s0 = as_v2h(sp[hp]);
      v2h s1 = as_v2h(sp[HH / 2 + hp]);
      v2h s2 = as_v2h(sp[2 * (HH / 2) + hp]);
      v2h s3 = as_v2h(sp[3 * (HH / 2) + hp]);
      a0 = __builtin_amdgcn_fdot2(__builtin_elementwise_max(s0 + q2, z2), wh, a0, false);
      a1 = __builtin_amdgcn_fdot2(__builtin_elementwise_max(s1 + q2, z2), wh, a1, false);
      a2 = __builtin_amdgcn_fdot2(__builtin_elementwise_max(s2 + q2, z2), wh, a2, false);
      a3 = __builtin_amdgcn_fdot2(__builtin_elementwise_max(s3 + q2, z2), wh, a3, false);
    }
#else
    #pragma unroll 8
    for (int hp = 0; hp < 64; ++hp) {
      v2h q2 = as_v2h(qp[hp * (BB * NN)]);
      v2h wh = as_v2h(wp[hp]);
      v2h s0 = as_v2h(sp[hp]);
      v2h s1 = as_v2h(sp[HH / 2 + hp]);
      v2h s2 = as_v2h(sp[2 * (HH / 2) + hp]);
      v2h s3 = as_v2h(sp[3 * (HH / 2) + hp]);
      float qx = (float)q2.x, qy = (float)q2.y;
      float wx = (float)wh.x, wy = (float)wh.y;
      a0 = fmaf(fmaxf((float)s0.x + qx, 0.f), wx, a0);
      a0 = fmaf(fmaxf((float)s0.y + qy, 0.f), wy, a0);
      a1 = fmaf(fmaxf((float)s1.x + qx, 0.f), wx, a1);
      a1 = fmaf(fmaxf((float)s1.y + qy, 0.f), wy, a1);
      a2 = fmaf(fmaxf((float)s2.x + qx, 0.f), wx, a2);
      a2 = fmaf(fmaxf((float)s2.y + qy, 0.f), wy, a2);
      a3 = fmaf(fmaxf((float)s3.x + qx, 0.f), wx, a3);
      a3 = fmaf(fmaxf((float)s3.y + qy, 0.f), wy, a3);
    }
#endif
    pe[hg][0][j] = a0; pe[hg][1][j] = a1;
    pe[hg][2][j] = a2; pe[hg][3][j] = a3;
  }
  __syncthreads();

  // ---- combine h-halves + bias + leaky + mask ----
  {
    const float b2v = b2[0];
    #pragma unroll
    for (int r = 0; r < 2; ++r) {
      int idx = t + 1024 * r;               // 2048 cells of [ti][j]
      int ti = idx >> 9, j2 = idx & 511;
      float e = pe[0][ti][j2] + pe[1][ti][j2] + b2v;
      e = e > 0.f ? e : 0.04f * e;
      int av = adj[(b * NN + i0 + ti) * NN + j2];
      e_l[ti][j2] = (av > 0) ? e : -9.0e15f;
    }
  }
  __syncthreads();

  // ---- softmax: wave = (ti = wv>>2, j-quarter = wv&3), 2 vals/lane ----
  {
    const int ti = wv >> 2, qtr = wv & 3;
    float2 v = *(float2*)&e_l[ti][qtr * 128 + 2 * ln];
    float m = fmaxf(v.x, v.y);
    #pragma unroll
    for (int off = 32; off > 0; off >>= 1) m = fmaxf(m, __shfl_xor(m, off, 64));
    if (ln == 0) red_m[ti][qtr] = m;
    __syncthreads();
    m = fmaxf(fmaxf(red_m[ti][0], red_m[ti][1]), fmaxf(red_m[ti][2], red_m[ti][3]));
    v.x = __expf(v.x - m); v.y = __expf(v.y - m);
    float zs = v.x + v.y;
    #pragma unroll
    for (int off = 32; off > 0; off >>= 1) zs += __shfl_xor(zs, off, 64);
    if (ln == 0) red_s[ti][qtr] = zs;
    __syncthreads();
    float inv = 1.f / ((red_s[ti][0] + red_s[ti][1]) + (red_s[ti][2] + red_s[ti][3]));
    v.x *= inv; v.y *= inv;
    *(float2*)&e_l[ti][qtr * 128 + 2 * ln] = v;
  }
  __syncthreads();

  // attention[0,0,:] extra output
  if (blk == 0 && t < NN) out[BB * NN * FF + t] = e_l[0][t];

  // ---- next_h: wave wv owns 32 j-rows (x read once per block); lane = f-pair ----
  {
    const int jb = wv * 32;
    const int f2 = 2 * ln;
    v2f acc[TI];
    #pragma unroll
    for (int ti = 0; ti < TI; ++ti) acc[ti] = (v2f){0.f, 0.f};

    #pragma unroll 2
    for (int g = 0; g < 8; ++g) {
      const int j0 = jb + g * 4;
      float4 aa[TI];
      #pragma unroll
      for (int ti = 0; ti < TI; ++ti) aa[ti] = *(float4*)&e_l[ti][j0];  // broadcast b128
      #pragma unroll
      for (int k = 0; k < 4; ++k) {
        v2f x2 = *(const v2f*)(x + (b * NN + j0 + k) * FF + f2);        // coalesced 512B
        #pragma unroll
        for (int ti = 0; ti < TI; ++ti) {
          float w = (k == 0) ? aa[ti].x : (k == 1) ? aa[ti].y : (k == 2) ? aa[ti].z : aa[ti].w;
          acc[ti] = __builtin_elementwise_fma(splat2(w), x2, acc[ti]);
        }
      }
    }
    #pragma unroll
    for (int ti = 0; ti < TI; ++ti) *(v2f*)&part_l[wv][ti][f2] = acc[ti];
  }
  __syncthreads();
  if (t < TI * FF) {                         // 512 cells
    const int ti = t >> 7, f = t & 127;
    float r = 0.f;
    #pragma unroll
    for (int w = 0; w < 16; ++w) r += part_l[w][ti][f];
    out[(b * NN + i0 + ti) * FF + f] = r;
  }
}

extern "C" void kernel_launch(void* const* d_in, const int* in_sizes, int n_in,
                              void* d_out, int out_size, void* d_ws, size_t ws_size,
                              hipStream_t stream) {
  const float* x   = (const float*)d_in[0];
  const float* w1  = (const float*)d_in[1];
  const float* b1  = (const float*)d_in[2];
  const float* w2  = (const float*)d_in[3];
  const float* b2  = (const float*)d_in[4];
  const int*   adj = (const int*)  d_in[5];
  float* out = (float*)d_out;

  u32* s16  = (u32*)d_ws;                   // [1024][128] u32 (f16 h-pairs) = 512 KB
  u32* q16  = s16 + BB * NN * (HH / 2);     // [128][1024] u32 = 512 KB
  u32* w216 = q16 + (HH / 2) * (BB * NN);   // [128] u32

  dim3 g1(BB * NN / 16, (2 * HH) / 64);     // (64, 8) = 512 blocks
  k1_pq  <<<g1, 256, 0, stream>>>(x, w1, b1, w2, s16, q16, w216);
  k2_attn<<<BB * NN / TI, 1024, 0, stream>>>(s16, q16, w216, x, b2, adj, out);
}